// Round 4
// baseline (493.084 us; speedup 1.0000x reference)
//
#include <hip/hip_runtime.h>
#include <hip/hip_bf16.h>

// ---------- types ----------
typedef __bf16    bf16x8_t __attribute__((ext_vector_type(8)));
typedef __bf16    bf16x4_t __attribute__((ext_vector_type(4)));
typedef float     f32x4_t  __attribute__((ext_vector_type(4)));
typedef _Float16  f16x8_t  __attribute__((ext_vector_type(8)));

static __device__ __forceinline__ f32x4_t mfma16(bf16x8_t a, bf16x8_t b, f32x4_t c) {
    return __builtin_amdgcn_mfma_f32_16x16x32_bf16(a, b, c, 0, 0, 0);
}

static __device__ __forceinline__ float redsum16(float v) {
#pragma unroll
    for (int off = 1; off < 16; off <<= 1) v += __shfl_xor(v, off);
    return v;
}

// async global->LDS 16B (m97 pattern)
static __device__ __forceinline__ void async16(const __bf16* g, __bf16* l) {
    __builtin_amdgcn_global_load_lds(
        (const __attribute__((address_space(1))) unsigned int*)g,
        (__attribute__((address_space(3))) unsigned int*)l, 16, 0, 0);
}

// ---------- fused fp32 -> bf16 convert, all 6 regions in one launch ----------
__global__ __launch_bounds__(256) void f2b_multi(const float* __restrict__ q,
                                                 const float* __restrict__ kv,
                                                 const float* __restrict__ wq,
                                                 const float* __restrict__ wk,
                                                 const float* __restrict__ wv,
                                                 const float* __restrict__ wo,
                                                 __bf16* __restrict__ qb,
                                                 __bf16* __restrict__ kvb,
                                                 __bf16* __restrict__ wqb,
                                                 __bf16* __restrict__ wkvb,
                                                 __bf16* __restrict__ wob,
                                                 float qscale) {
    int i = blockIdx.x * 256 + threadIdx.x;   // float4 index, 0..4194303
    const float* src; __bf16* dst; int base; float scale = 1.0f;
    if (i < 1048576)      { src = q;  dst = qb;   base = 0; }
    else if (i < 3145728) { src = kv; dst = kvb;  base = 1048576; }
    else if (i < 3407872) { src = wq; dst = wqb;  base = 3145728; scale = qscale; }
    else if (i < 3670016) { src = wk; dst = wkvb; base = 3407872; }
    else if (i < 3932160) { src = wv; dst = wkvb + 1048576; base = 3670016; }
    else                  { src = wo; dst = wob;  base = 3932160; }
    int j = i - base;
    float4 v = reinterpret_cast<const float4*>(src)[j];
    bf16x4_t o;
    o[0] = (__bf16)(v.x * scale); o[1] = (__bf16)(v.y * scale);
    o[2] = (__bf16)(v.z * scale); o[3] = (__bf16)(v.w * scale);
    reinterpret_cast<bf16x4_t*>(dst)[j] = o;
}

// ---------- GEMM: C[M,N] = A[M,K] * B[N,K]^T ----------
// 128x128 tile, BK=32, 256 threads, global_load_lds staging.
// OMAP 0: plain row-major. OMAP 1: merged K/V projection (Kh + imp-scaled permuted Vh).
template <int OMAP, typename CT>
__global__ __launch_bounds__(256) void gemm_bt_kernel(const __bf16* __restrict__ A,
                                                      const __bf16* __restrict__ B,
                                                      CT* __restrict__ C,
                                                      int M, int N, int K,
                                                      __bf16* __restrict__ V2,
                                                      const float* __restrict__ imp) {
    __shared__ __bf16 As[128 * 32];
    __shared__ __bf16 Bs[128 * 32];

    const int t    = threadIdx.x;
    const int w    = t >> 6;
    const int lane = t & 63;
    const int quad = lane >> 4;
    const int mn   = lane & 15;
    const int wm   = (w & 1) * 64;
    const int wn   = (w >> 1) * 64;
    const long m0  = (long)blockIdx.y * 128;
    const long n0  = (long)blockIdx.x * 128;

    const int  srow = t >> 2;
    const int  scol = (t & 3) * 8;
    const __bf16* gA = A + (m0 + srow) * (long)K + scol;
    const __bf16* gB = B + (n0 + srow) * (long)K + scol;

    f32x4_t acc[4][4];
#pragma unroll
    for (int i = 0; i < 4; i++)
#pragma unroll
        for (int j = 0; j < 4; j++) acc[i][j] = (f32x4_t){0.f, 0.f, 0.f, 0.f};

    for (int k0 = 0; k0 < K; k0 += 32) {
        __syncthreads();
        async16(gA + k0,                &As[t * 8]);
        async16(gA + (long)64 * K + k0, &As[2048 + t * 8]);
        async16(gB + k0,                &Bs[t * 8]);
        async16(gB + (long)64 * K + k0, &Bs[2048 + t * 8]);
        __syncthreads();

        bf16x8_t af[4], bf[4];
#pragma unroll
        for (int i = 0; i < 4; i++)
            af[i] = *(const bf16x8_t*)&As[(wm + i * 16 + mn) * 32 + quad * 8];
#pragma unroll
        for (int j = 0; j < 4; j++)
            bf[j] = *(const bf16x8_t*)&Bs[(wn + j * 16 + mn) * 32 + quad * 8];
#pragma unroll
        for (int i = 0; i < 4; i++)
#pragma unroll
            for (int j = 0; j < 4; j++) acc[i][j] = mfma16(af[i], bf[j], acc[i][j]);
    }

#pragma unroll
    for (int i = 0; i < 4; i++)
#pragma unroll
        for (int j = 0; j < 4; j++)
#pragma unroll
            for (int r = 0; r < 4; r++) {
                long row = m0 + wm + i * 16 + quad * 4 + r;
                long col = n0 + wn + j * 16 + mn;
                float v = acc[i][j][r];
                if (OMAP == 0) {
                    C[row * N + col] = (CT)v;
                } else {
                    int b_ = (int)(row >> 12), s_ = (int)(row & 4095);
                    if (col < 1024) {
                        int h_ = (int)(col >> 6), d_ = (int)(col & 63);
                        C[(long)(b_ * 16 + h_) * 262144 + (long)s_ * 64 + d_] = (CT)v;
                    } else {
                        int c  = (int)col - 1024;
                        int h_ = c >> 6, d_ = c & 63;
                        int st = s_ >> 6, sl = s_ & 63;
                        int p  = (sl & 15) * 4 + (sl >> 4);
                        float sc_ = fmaxf(imp[b_ * 16 + (s_ & 15)], 1e-6f);
                        V2[(long)(b_ * 16 + h_) * 262144 + (long)st * 4096 + d_ * 64 + p] =
                            (__bf16)(v * sc_);
                    }
                }
            }
}

// ---------- barrier-free, shuffle-free flash attention, S-split x2 ----------
// 1D grid 1024 blocks, XCD-swizzled: gid = (bh&7) | qt<<3 | sp<<7 | (bh>>3)<<8.
// Each block: 4 independent waves x 32 q-rows, sweeps half of S (2048).
// Writes unnormalized fp16 o-partials + per-row l to workspace (fixed-m softmax
// => partials combine additively; no rescale needed).
__global__ __launch_bounds__(256, 4) void attn_kernel(const __bf16* __restrict__ Qp,
                                                      const __bf16* __restrict__ Kh,
                                                      const __bf16* __restrict__ Vh,
                                                      const float* __restrict__ imp,
                                                      _Float16* __restrict__ Op,
                                                      float* __restrict__ Lp) {
    const int gid = blockIdx.x;
    const int qt  = (gid >> 3) & 15;
    const int sp  = (gid >> 7) & 1;
    const int bh  = ((gid >> 8) << 3) | (gid & 7);
    const int b   = bh >> 4;
    const int h   = bh & 15;
    const int t    = threadIdx.x;
    const int w    = t >> 6;
    const int lane = t & 63;
    const int quad = lane >> 4;
    const int mn   = lane & 15;

    __shared__ __bf16 Ps[4][32][72];   // per-wave P strip (wave-local; no barriers)

    const long qrow0 = (long)b * 2048 + qt * 128 + w * 32;
    const __bf16* Kb = Kh + (long)bh * 262144;
    const __bf16* Vb = Vh + (long)bh * 262144;

    bf16x8_t aq[2][2];
#pragma unroll
    for (int rt = 0; rt < 2; rt++)
#pragma unroll
        for (int x = 0; x < 2; x++)
            aq[rt][x] = *(const bf16x8_t*)&Qp[(qrow0 + rt * 16 + mn) * 1024 + h * 64 + x * 32 + quad * 8];

    const float impc = fmaxf(imp[b * 16 + mn], 1e-6f);

    float lpart[2][4];
    f32x4_t o[2][4];
#pragma unroll
    for (int rt = 0; rt < 2; rt++)
#pragma unroll
        for (int r = 0; r < 4; r++) lpart[rt][r] = 0.f;
#pragma unroll
    for (int rt = 0; rt < 2; rt++)
#pragma unroll
        for (int dt = 0; dt < 4; dt++) o[rt][dt] = (f32x4_t){0.f, 0.f, 0.f, 0.f};

    for (int st = sp * 32; st < sp * 32 + 32; st++) {
        const int s0 = st * 64;
        bf16x8_t bk0[4], bk1[4], bv0[4], bv1[4];
#pragma unroll
        for (int ct = 0; ct < 4; ct++) {
            const __bf16* kr = &Kb[(long)(s0 + ct * 16 + mn) * 64 + quad * 8];
            bk0[ct] = *(const bf16x8_t*)kr;
            bk1[ct] = *(const bf16x8_t*)(kr + 32);
        }
#pragma unroll
        for (int dt = 0; dt < 4; dt++) {
            const __bf16* vr = &Vb[(long)st * 4096 + (dt * 16 + mn) * 64 + quad * 8];
            bv0[dt] = *(const bf16x8_t*)vr;
            bv1[dt] = *(const bf16x8_t*)(vr + 32);
        }

#pragma unroll
        for (int rt = 0; rt < 2; rt++) {
            f32x4_t sc[4];
#pragma unroll
            for (int ct = 0; ct < 4; ct++) sc[ct] = (f32x4_t){0.f, 0.f, 0.f, 0.f};
#pragma unroll
            for (int ct = 0; ct < 4; ct++) {
                sc[ct] = mfma16(aq[rt][0], bk0[ct], sc[ct]);
                sc[ct] = mfma16(aq[rt][1], bk1[ct], sc[ct]);
            }

#pragma unroll
            for (int r = 0; r < 4; r++) {
                float p0 = __builtin_amdgcn_exp2f(sc[0][r]);
                float p1 = __builtin_amdgcn_exp2f(sc[1][r]);
                float p2 = __builtin_amdgcn_exp2f(sc[2][r]);
                float p3 = __builtin_amdgcn_exp2f(sc[3][r]);
                lpart[rt][r] += (p0 + p1) + (p2 + p3);
                bf16x4_t pk;
                pk[0] = (__bf16)p0; pk[1] = (__bf16)p1;
                pk[2] = (__bf16)p2; pk[3] = (__bf16)p3;
                *(bf16x4_t*)&Ps[w][rt * 16 + quad * 4 + r][mn * 4] = pk;
            }

            bf16x8_t ap0 = *(const bf16x8_t*)&Ps[w][rt * 16 + mn][quad * 8];
            bf16x8_t ap1 = *(const bf16x8_t*)&Ps[w][rt * 16 + mn][32 + quad * 8];
#pragma unroll
            for (int dt = 0; dt < 4; dt++) {
                o[rt][dt] = mfma16(ap0, bv0[dt], o[rt][dt]);
                o[rt][dt] = mfma16(ap1, bv1[dt], o[rt][dt]);
            }
        }
    }

    // epilogue: per-row l (one reduction), unnormalized fp16 o-partials
#pragma unroll
    for (int rt = 0; rt < 2; rt++)
#pragma unroll
        for (int r = 0; r < 4; r++) {
            float l = redsum16(lpart[rt][r] * impc);
            long row = qrow0 + rt * 16 + quad * 4 + r;
            if (mn == 0) Lp[((long)sp * 4096 + row) * 16 + h] = l;
#pragma unroll
            for (int dt = 0; dt < 4; dt++)
                Op[((long)sp * 4096 + row) * 1024 + h * 64 + dt * 16 + mn] =
                    (_Float16)o[rt][dt][r];
        }
}

// ---------- combine: Y = (o0+o1)/(l0+l1), fp16 partials -> bf16 ----------
__global__ __launch_bounds__(256) void combine_kernel(const _Float16* __restrict__ Op,
                                                      const float* __restrict__ Lp,
                                                      __bf16* __restrict__ Y) {
    int tid = blockIdx.x * 256 + threadIdx.x;  // 0..524287
    int row = tid >> 7;
    int cg  = tid & 127;
    int h   = cg >> 3;
    f16x8_t o0 = *(const f16x8_t*)&Op[(long)row * 1024 + cg * 8];
    f16x8_t o1 = *(const f16x8_t*)&Op[(long)(4096 + row) * 1024 + cg * 8];
    float inv = 1.0f / (Lp[row * 16 + h] + Lp[(4096 + row) * 16 + h]);
    bf16x8_t y;
#pragma unroll
    for (int j = 0; j < 8; j++) y[j] = (__bf16)(((float)o0[j] + (float)o1[j]) * inv);
    *(bf16x8_t*)&Y[(long)row * 1024 + cg * 8] = y;
}

// ---------- launch ----------
extern "C" void kernel_launch(void* const* d_in, const int* in_sizes, int n_in,
                              void* d_out, int out_size, void* d_ws, size_t ws_size,
                              hipStream_t stream) {
    const float* q_f  = (const float*)d_in[0];
    const float* kv_f = (const float*)d_in[1];
    const float* imp  = (const float*)d_in[2];
    const float* wq_f = (const float*)d_in[3];
    const float* wk_f = (const float*)d_in[4];
    const float* wv_f = (const float*)d_in[5];
    const float* wo_f = (const float*)d_in[6];

    char* ws = (char*)d_ws;
    const size_t MB = 1ull << 20;
    // dynamic region [0, 30MB): stage A (projection inputs) then stage B (partials/Y)
    __bf16*   qb    = (__bf16*)(ws + 0);            // 8 MB   (stage A)
    __bf16*   kvb   = (__bf16*)(ws + 8 * MB);       // 16 MB  (stage A)
    __bf16*   wqb   = (__bf16*)(ws + 24 * MB);      // 2 MB   (stage A)
    __bf16*   wkvb  = (__bf16*)(ws + 26 * MB);      // 4 MB   (stage A)
    _Float16* Opart = (_Float16*)(ws + 0);          // 16 MB  (stage B, attn out)
    float*    Lpart = (float*)(ws + 16 * MB);       // 0.5 MB (stage B)
    __bf16*   Yb    = (__bf16*)(ws + 17 * MB);      // 8 MB   (stage B, combine out)
    // static region
    __bf16*   wob   = (__bf16*)(ws + 30 * MB);      // 2 MB
    __bf16*   Qp    = (__bf16*)(ws + 32 * MB);      // 8 MB
    __bf16*   Khd   = (__bf16*)(ws + 40 * MB);      // 16 MB
    __bf16*   Vhd   = (__bf16*)(ws + 56 * MB);      // 16 MB  -> total 72 MB

    const float QSCALE = 0.125f * 1.4426950408889634f;  // 1/sqrt(64)*log2(e), folded into Wq

    f2b_multi<<<16384, 256, 0, stream>>>(q_f, kv_f, wq_f, wk_f, wv_f, wo_f,
                                         qb, kvb, wqb, wkvb, wob, QSCALE);

    gemm_bt_kernel<0, __bf16><<<dim3(8, 32), 256, 0, stream>>>(qb, wqb, Qp, 4096, 1024, 1024,
                                                               nullptr, nullptr);
    gemm_bt_kernel<1, __bf16><<<dim3(16, 64), 256, 0, stream>>>(kvb, wkvb, Khd, 8192, 2048, 1024,
                                                                Vhd, imp);

    attn_kernel<<<1024, 256, 0, stream>>>(Qp, Khd, Vhd, imp, Opart, Lpart);
    combine_kernel<<<2048, 256, 0, stream>>>(Opart, Lpart, Yb);

    gemm_bt_kernel<0, float><<<dim3(8, 32), 256, 0, stream>>>(Yb, wob, (float*)d_out, 4096, 1024, 1024,
                                                              nullptr, nullptr);
}

// Round 5
// 337.935 us; speedup vs baseline: 1.4591x; 1.4591x over previous
//
#include <hip/hip_runtime.h>
#include <hip/hip_bf16.h>

// ---------- types ----------
typedef __bf16    bf16x8_t __attribute__((ext_vector_type(8)));
typedef __bf16    bf16x4_t __attribute__((ext_vector_type(4)));
typedef float     f32x4_t  __attribute__((ext_vector_type(4)));
typedef _Float16  f16x8_t  __attribute__((ext_vector_type(8)));

static __device__ __forceinline__ f32x4_t mfma16(bf16x8_t a, bf16x8_t b, f32x4_t c) {
    return __builtin_amdgcn_mfma_f32_16x16x32_bf16(a, b, c, 0, 0, 0);
}

static __device__ __forceinline__ float redsum16(float v) {
#pragma unroll
    for (int off = 1; off < 16; off <<= 1) v += __shfl_xor(v, off);
    return v;
}

// async global->LDS 16B (m97 pattern); lds pointer must be wave-uniform
static __device__ __forceinline__ void async16(const __bf16* g, __bf16* l) {
    __builtin_amdgcn_global_load_lds(
        (const __attribute__((address_space(1))) unsigned int*)g,
        (__attribute__((address_space(3))) unsigned int*)l, 16, 0, 0);
}

// ---------- fused fp32 -> bf16 convert ----------
__global__ __launch_bounds__(256) void f2b_multi(const float* __restrict__ q,
                                                 const float* __restrict__ kv,
                                                 const float* __restrict__ wq,
                                                 const float* __restrict__ wk,
                                                 const float* __restrict__ wv,
                                                 const float* __restrict__ wo,
                                                 __bf16* __restrict__ qb,
                                                 __bf16* __restrict__ kvb,
                                                 __bf16* __restrict__ wqb,
                                                 __bf16* __restrict__ wkvb,
                                                 __bf16* __restrict__ wob,
                                                 float qscale) {
    int i = blockIdx.x * 256 + threadIdx.x;
    const float* src; __bf16* dst; int base; float scale = 1.0f;
    if (i < 1048576)      { src = q;  dst = qb;   base = 0; }
    else if (i < 3145728) { src = kv; dst = kvb;  base = 1048576; }
    else if (i < 3407872) { src = wq; dst = wqb;  base = 3145728; scale = qscale; }
    else if (i < 3670016) { src = wk; dst = wkvb; base = 3407872; }
    else if (i < 3932160) { src = wv; dst = wkvb + 1048576; base = 3670016; }
    else                  { src = wo; dst = wob;  base = 3932160; }
    int j = i - base;
    float4 v = reinterpret_cast<const float4*>(src)[j];
    bf16x4_t o;
    o[0] = (__bf16)(v.x * scale); o[1] = (__bf16)(v.y * scale);
    o[2] = (__bf16)(v.z * scale); o[3] = (__bf16)(v.w * scale);
    reinterpret_cast<bf16x4_t*>(dst)[j] = o;
}

// ---------- GEMM: C[M,N] = A[M,K] * B[N,K]^T ----------
template <int OMAP, typename CT>
__global__ __launch_bounds__(256) void gemm_bt_kernel(const __bf16* __restrict__ A,
                                                      const __bf16* __restrict__ B,
                                                      CT* __restrict__ C,
                                                      int M, int N, int K,
                                                      __bf16* __restrict__ V2,
                                                      const float* __restrict__ imp) {
    __shared__ __bf16 As[128 * 32];
    __shared__ __bf16 Bs[128 * 32];

    const int t    = threadIdx.x;
    const int w    = t >> 6;
    const int lane = t & 63;
    const int quad = lane >> 4;
    const int mn   = lane & 15;
    const int wm   = (w & 1) * 64;
    const int wn   = (w >> 1) * 64;
    const long m0  = (long)blockIdx.y * 128;
    const long n0  = (long)blockIdx.x * 128;

    const int  srow = t >> 2;
    const int  scol = (t & 3) * 8;
    const __bf16* gA = A + (m0 + srow) * (long)K + scol;
    const __bf16* gB = B + (n0 + srow) * (long)K + scol;

    f32x4_t acc[4][4];
#pragma unroll
    for (int i = 0; i < 4; i++)
#pragma unroll
        for (int j = 0; j < 4; j++) acc[i][j] = (f32x4_t){0.f, 0.f, 0.f, 0.f};

    for (int k0 = 0; k0 < K; k0 += 32) {
        __syncthreads();
        async16(gA + k0,                &As[t * 8]);
        async16(gA + (long)64 * K + k0, &As[2048 + t * 8]);
        async16(gB + k0,                &Bs[t * 8]);
        async16(gB + (long)64 * K + k0, &Bs[2048 + t * 8]);
        __syncthreads();

        bf16x8_t af[4], bf[4];
#pragma unroll
        for (int i = 0; i < 4; i++)
            af[i] = *(const bf16x8_t*)&As[(wm + i * 16 + mn) * 32 + quad * 8];
#pragma unroll
        for (int j = 0; j < 4; j++)
            bf[j] = *(const bf16x8_t*)&Bs[(wn + j * 16 + mn) * 32 + quad * 8];
#pragma unroll
        for (int i = 0; i < 4; i++)
#pragma unroll
            for (int j = 0; j < 4; j++) acc[i][j] = mfma16(af[i], bf[j], acc[i][j]);
    }

#pragma unroll
    for (int i = 0; i < 4; i++)
#pragma unroll
        for (int j = 0; j < 4; j++)
#pragma unroll
            for (int r = 0; r < 4; r++) {
                long row = m0 + wm + i * 16 + quad * 4 + r;
                long col = n0 + wn + j * 16 + mn;
                float v = acc[i][j][r];
                if (OMAP == 0) {
                    C[row * N + col] = (CT)v;
                } else {
                    int b_ = (int)(row >> 12), s_ = (int)(row & 4095);
                    if (col < 1024) {
                        int h_ = (int)(col >> 6), d_ = (int)(col & 63);
                        C[(long)(b_ * 16 + h_) * 262144 + (long)s_ * 64 + d_] = (CT)v;
                    } else {
                        int c  = (int)col - 1024;
                        int h_ = c >> 6, d_ = c & 63;
                        int st = s_ >> 6, sl = s_ & 63;
                        int p  = (sl & 15) * 4 + (sl >> 4);
                        float sc_ = fmaxf(imp[b_ * 16 + (s_ & 15)], 1e-6f);
                        V2[(long)(b_ * 16 + h_) * 262144 + (long)st * 4096 + d_ * 64 + p] =
                            (__bf16)(v * sc_);
                    }
                }
            }
}

// ---------- flash attention: LDS-staged K/V (coalesced async16 + XOR swizzle) ----------
// 1D grid 1024 blocks, XCD-swizzled: gid = (bh&7) | qt<<3 | sp<<7 | (bh>>3)<<8.
// Block: 4 waves x 32 q-rows, sweeps half of S. K/V tiles (8KB each) staged once per
// block per iter via global_load_lds; LDS rows hold chunk c at slot c^(r&7) so
// fragment ds_read_b128 is 2-way-conflict-free (free per m136).
__global__ __launch_bounds__(256, 4) void attn_kernel(const __bf16* __restrict__ Qp,
                                                      const __bf16* __restrict__ Kh,
                                                      const __bf16* __restrict__ Vh,
                                                      const float* __restrict__ imp,
                                                      _Float16* __restrict__ Op,
                                                      float* __restrict__ Lp) {
    const int gid = blockIdx.x;
    const int qt  = (gid >> 3) & 15;
    const int sp  = (gid >> 7) & 1;
    const int bh  = ((gid >> 8) << 3) | (gid & 7);
    const int b   = bh >> 4;
    const int h   = bh & 15;
    const int t    = threadIdx.x;
    const int w    = t >> 6;
    const int lane = t & 63;
    const int quad = lane >> 4;
    const int mn   = lane & 15;

    __shared__ __bf16 Ks[64 * 64];     // 8KB, XOR-swizzled rows of 128B
    __shared__ __bf16 Vs[64 * 64];     // 8KB, XOR-swizzled
    __shared__ __bf16 Ps[4][32][72];   // per-wave P strip

    const long qrow0 = (long)b * 2048 + qt * 128 + w * 32;
    const __bf16* Kb = Kh + (long)bh * 262144;
    const __bf16* Vb = Vh + (long)bh * 262144;

    // staging geometry: per call, wave w covers 1KB block bidx = j*4+w (rows bidx*8..+7)
    const int r8 = lane >> 3;            // row within 1KB block
    const int cs = (lane & 7) ^ r8;      // swizzled source chunk (16B units)
    const int srcoff0 = (0 * 4 + w) * 512 + r8 * 64 + cs * 8;   // elements
    const int srcoff1 = (1 * 4 + w) * 512 + r8 * 64 + cs * 8;
    __bf16* ldsK0 = Ks + (0 * 4 + w) * 512;   // wave-uniform dests
    __bf16* ldsK1 = Ks + (1 * 4 + w) * 512;
    __bf16* ldsV0 = Vs + (0 * 4 + w) * 512;
    __bf16* ldsV1 = Vs + (1 * 4 + w) * 512;

    bf16x8_t aq[2][2];
#pragma unroll
    for (int rt = 0; rt < 2; rt++)
#pragma unroll
        for (int x = 0; x < 2; x++)
            aq[rt][x] = *(const bf16x8_t*)&Qp[(qrow0 + rt * 16 + mn) * 1024 + h * 64 + x * 32 + quad * 8];

    const float impc = fmaxf(imp[b * 16 + mn], 1e-6f);

    float lpart[2][4];
    f32x4_t o[2][4];
#pragma unroll
    for (int rt = 0; rt < 2; rt++)
#pragma unroll
        for (int r = 0; r < 4; r++) lpart[rt][r] = 0.f;
#pragma unroll
    for (int rt = 0; rt < 2; rt++)
#pragma unroll
        for (int dt = 0; dt < 4; dt++) o[rt][dt] = (f32x4_t){0.f, 0.f, 0.f, 0.f};

    // fragment LDS offsets (swizzle-aware): row s, chunk quad -> s*64 + ((quad^(s&7))*8
    // K rows: s = ct*16+mn ; V rows: d = dt*16+mn ; second half chunk = first ^ 4.

    for (int st = sp * 32; st < sp * 32 + 32; st++) {
        const long kbase = (long)st * 4096;   // 64 rows * 64 elements
        __syncthreads();                       // prior iter done reading Ks/Vs
        async16(Kb + kbase + srcoff0, ldsK0);
        async16(Kb + kbase + srcoff1, ldsK1);
        async16(Vb + kbase + srcoff0, ldsV0);
        async16(Vb + kbase + srcoff1, ldsV1);
        __syncthreads();                       // drain vmcnt -> tiles visible

        // ---- K fragments, QK^T ----
        f32x4_t sc[2][4];
        {
            bf16x8_t bk0[4], bk1[4];
#pragma unroll
            for (int ct = 0; ct < 4; ct++) {
                int s  = ct * 16 + mn;
                int c0 = (quad ^ (s & 7)) * 8;
                bk0[ct] = *(const bf16x8_t*)&Ks[s * 64 + c0];
                bk1[ct] = *(const bf16x8_t*)&Ks[s * 64 + (c0 ^ 32)];   // chunk^4 = +/-64B
            }
#pragma unroll
            for (int rt = 0; rt < 2; rt++) {
#pragma unroll
                for (int ct = 0; ct < 4; ct++) sc[rt][ct] = (f32x4_t){0.f, 0.f, 0.f, 0.f};
#pragma unroll
                for (int ct = 0; ct < 4; ct++) {
                    sc[rt][ct] = mfma16(aq[rt][0], bk0[ct], sc[rt][ct]);
                    sc[rt][ct] = mfma16(aq[rt][1], bk1[ct], sc[rt][ct]);
                }
            }
        }

        // ---- softmax body (shuffle-free, fixed m=0), write P strips ----
#pragma unroll
        for (int rt = 0; rt < 2; rt++)
#pragma unroll
            for (int r = 0; r < 4; r++) {
                float p0 = __builtin_amdgcn_exp2f(sc[rt][0][r]);
                float p1 = __builtin_amdgcn_exp2f(sc[rt][1][r]);
                float p2 = __builtin_amdgcn_exp2f(sc[rt][2][r]);
                float p3 = __builtin_amdgcn_exp2f(sc[rt][3][r]);
                lpart[rt][r] += (p0 + p1) + (p2 + p3);
                bf16x4_t pk;
                pk[0] = (__bf16)p0; pk[1] = (__bf16)p1;
                pk[2] = (__bf16)p2; pk[3] = (__bf16)p3;
                *(bf16x4_t*)&Ps[w][rt * 16 + quad * 4 + r][mn * 4] = pk;
            }

        // ---- V + P fragments, PV ----
        {
            bf16x8_t bv0[4], bv1[4];
#pragma unroll
            for (int dt = 0; dt < 4; dt++) {
                int d  = dt * 16 + mn;
                int c0 = (quad ^ (d & 7)) * 8;
                bv0[dt] = *(const bf16x8_t*)&Vs[d * 64 + c0];
                bv1[dt] = *(const bf16x8_t*)&Vs[d * 64 + (c0 ^ 32)];
            }
#pragma unroll
            for (int rt = 0; rt < 2; rt++) {
                bf16x8_t ap0 = *(const bf16x8_t*)&Ps[w][rt * 16 + mn][quad * 8];
                bf16x8_t ap1 = *(const bf16x8_t*)&Ps[w][rt * 16 + mn][32 + quad * 8];
#pragma unroll
                for (int dt = 0; dt < 4; dt++) {
                    o[rt][dt] = mfma16(ap0, bv0[dt], o[rt][dt]);
                    o[rt][dt] = mfma16(ap1, bv1[dt], o[rt][dt]);
                }
            }
        }
    }

    // epilogue: per-row l, unnormalized fp16 partials
#pragma unroll
    for (int rt = 0; rt < 2; rt++)
#pragma unroll
        for (int r = 0; r < 4; r++) {
            float l = redsum16(lpart[rt][r] * impc);
            long row = qrow0 + rt * 16 + quad * 4 + r;
            if (mn == 0) Lp[((long)sp * 4096 + row) * 16 + h] = l;
#pragma unroll
            for (int dt = 0; dt < 4; dt++)
                Op[((long)sp * 4096 + row) * 1024 + h * 64 + dt * 16 + mn] =
                    (_Float16)o[rt][dt][r];
        }
}

// ---------- combine: Y = (o0+o1)/(l0+l1) ----------
__global__ __launch_bounds__(256) void combine_kernel(const _Float16* __restrict__ Op,
                                                      const float* __restrict__ Lp,
                                                      __bf16* __restrict__ Y) {
    int tid = blockIdx.x * 256 + threadIdx.x;
    int row = tid >> 7;
    int cg  = tid & 127;
    int h   = cg >> 3;
    f16x8_t o0 = *(const f16x8_t*)&Op[(long)row * 1024 + cg * 8];
    f16x8_t o1 = *(const f16x8_t*)&Op[(long)(4096 + row) * 1024 + cg * 8];
    float inv = 1.0f / (Lp[row * 16 + h] + Lp[(4096 + row) * 16 + h]);
    bf16x8_t y;
#pragma unroll
    for (int j = 0; j < 8; j++) y[j] = (__bf16)(((float)o0[j] + (float)o1[j]) * inv);
    *(bf16x8_t*)&Y[(long)row * 1024 + cg * 8] = y;
}

// ---------- launch ----------
extern "C" void kernel_launch(void* const* d_in, const int* in_sizes, int n_in,
                              void* d_out, int out_size, void* d_ws, size_t ws_size,
                              hipStream_t stream) {
    const float* q_f  = (const float*)d_in[0];
    const float* kv_f = (const float*)d_in[1];
    const float* imp  = (const float*)d_in[2];
    const float* wq_f = (const float*)d_in[3];
    const float* wk_f = (const float*)d_in[4];
    const float* wv_f = (const float*)d_in[5];
    const float* wo_f = (const float*)d_in[6];

    char* ws = (char*)d_ws;
    const size_t MB = 1ull << 20;
    __bf16*   qb    = (__bf16*)(ws + 0);            // 8 MB   (stage A)
    __bf16*   kvb   = (__bf16*)(ws + 8 * MB);       // 16 MB  (stage A)
    __bf16*   wqb   = (__bf16*)(ws + 24 * MB);      // 2 MB   (stage A)
    __bf16*   wkvb  = (__bf16*)(ws + 26 * MB);      // 4 MB   (stage A)
    _Float16* Opart = (_Float16*)(ws + 0);          // 16 MB  (stage B)
    float*    Lpart = (float*)(ws + 16 * MB);       // 0.5 MB (stage B)
    __bf16*   Yb    = (__bf16*)(ws + 17 * MB);      // 8 MB   (stage B)
    __bf16*   wob   = (__bf16*)(ws + 30 * MB);      // 2 MB
    __bf16*   Qp    = (__bf16*)(ws + 32 * MB);      // 8 MB
    __bf16*   Khd   = (__bf16*)(ws + 40 * MB);      // 16 MB
    __bf16*   Vhd   = (__bf16*)(ws + 56 * MB);      // 16 MB

    const float QSCALE = 0.125f * 1.4426950408889634f;

    f2b_multi<<<16384, 256, 0, stream>>>(q_f, kv_f, wq_f, wk_f, wv_f, wo_f,
                                         qb, kvb, wqb, wkvb, wob, QSCALE);

    gemm_bt_kernel<0, __bf16><<<dim3(8, 32), 256, 0, stream>>>(qb, wqb, Qp, 4096, 1024, 1024,
                                                               nullptr, nullptr);
    gemm_bt_kernel<1, __bf16><<<dim3(16, 64), 256, 0, stream>>>(kvb, wkvb, Khd, 8192, 2048, 1024,
                                                                Vhd, imp);

    attn_kernel<<<1024, 256, 0, stream>>>(Qp, Khd, Vhd, imp, Opart, Lpart);
    combine_kernel<<<2048, 256, 0, stream>>>(Opart, Lpart, Yb);

    gemm_bt_kernel<0, float><<<dim3(8, 32), 256, 0, stream>>>(Yb, wob, (float*)d_out, 4096, 1024, 1024,
                                                              nullptr, nullptr);
}

// Round 6
// 299.233 us; speedup vs baseline: 1.6478x; 1.1293x over previous
//
#include <hip/hip_runtime.h>
#include <hip/hip_bf16.h>

// ---------- types ----------
typedef __bf16    bf16x8_t __attribute__((ext_vector_type(8)));
typedef __bf16    bf16x4_t __attribute__((ext_vector_type(4)));
typedef float     f32x4_t  __attribute__((ext_vector_type(4)));
typedef _Float16  f16x8_t  __attribute__((ext_vector_type(8)));

static __device__ __forceinline__ f32x4_t mfma16(bf16x8_t a, bf16x8_t b, f32x4_t c) {
    return __builtin_amdgcn_mfma_f32_16x16x32_bf16(a, b, c, 0, 0, 0);
}

static __device__ __forceinline__ float redsum16(float v) {
#pragma unroll
    for (int off = 1; off < 16; off <<= 1) v += __shfl_xor(v, off);
    return v;
}

// async global->LDS 16B (m97 pattern); lds pointer must be wave-uniform
static __device__ __forceinline__ void async16(const __bf16* g, __bf16* l) {
    __builtin_amdgcn_global_load_lds(
        (const __attribute__((address_space(1))) unsigned int*)g,
        (__attribute__((address_space(3))) unsigned int*)l, 16, 0, 0);
}

// ---------- fused fp32 -> bf16 convert ----------
__global__ __launch_bounds__(256) void f2b_multi(const float* __restrict__ q,
                                                 const float* __restrict__ kv,
                                                 const float* __restrict__ wq,
                                                 const float* __restrict__ wk,
                                                 const float* __restrict__ wv,
                                                 const float* __restrict__ wo,
                                                 __bf16* __restrict__ qb,
                                                 __bf16* __restrict__ kvb,
                                                 __bf16* __restrict__ wqb,
                                                 __bf16* __restrict__ wkvb,
                                                 __bf16* __restrict__ wob,
                                                 float qscale) {
    int i = blockIdx.x * 256 + threadIdx.x;
    const float* src; __bf16* dst; int base; float scale = 1.0f;
    if (i < 1048576)      { src = q;  dst = qb;   base = 0; }
    else if (i < 3145728) { src = kv; dst = kvb;  base = 1048576; }
    else if (i < 3407872) { src = wq; dst = wqb;  base = 3145728; scale = qscale; }
    else if (i < 3670016) { src = wk; dst = wkvb; base = 3407872; }
    else if (i < 3932160) { src = wv; dst = wkvb + 1048576; base = 3670016; }
    else                  { src = wo; dst = wob;  base = 3932160; }
    int j = i - base;
    float4 v = reinterpret_cast<const float4*>(src)[j];
    bf16x4_t o;
    o[0] = (__bf16)(v.x * scale); o[1] = (__bf16)(v.y * scale);
    o[2] = (__bf16)(v.z * scale); o[3] = (__bf16)(v.w * scale);
    reinterpret_cast<bf16x4_t*>(dst)[j] = o;
}

// ---------- GEMM: C[M,N] = A[M,K] * B[N,K]^T ----------
// OMAP 0: row-major fp32 out, direct scalar stores.
// OMAP 1: merged K/V projection; block entirely K-part (blockIdx.x<8) or V-part.
//         LDS-staged epilogue -> each wave stores one contiguous 8KB block.
// OMAP 2: row-major bf16 out, LDS-staged epilogue (coalesced 128B row chunks).
template <int OMAP, typename CT>
__global__ __launch_bounds__(256) void gemm_bt_kernel(const __bf16* __restrict__ A,
                                                      const __bf16* __restrict__ B,
                                                      CT* __restrict__ C,
                                                      int M, int N, int K,
                                                      __bf16* __restrict__ V2,
                                                      const float* __restrict__ imp) {
    __shared__ __bf16 As[128 * 32];
    __shared__ __bf16 Bs[128 * 32];
    __shared__ __bf16 Es[2][4096];   // staging for waves 2,3 (waves 0,1 reuse As,Bs)

    const int t    = threadIdx.x;
    const int w    = t >> 6;
    const int lane = t & 63;
    const int quad = lane >> 4;
    const int mn   = lane & 15;
    const int wm   = (w & 1) * 64;
    const int wn   = (w >> 1) * 64;
    const long m0  = (long)blockIdx.y * 128;
    const long n0  = (long)blockIdx.x * 128;

    const int  srow = t >> 2;
    const int  scol = (t & 3) * 8;
    const __bf16* gA = A + (m0 + srow) * (long)K + scol;
    const __bf16* gB = B + (n0 + srow) * (long)K + scol;

    f32x4_t acc[4][4];
#pragma unroll
    for (int i = 0; i < 4; i++)
#pragma unroll
        for (int j = 0; j < 4; j++) acc[i][j] = (f32x4_t){0.f, 0.f, 0.f, 0.f};

    for (int k0 = 0; k0 < K; k0 += 32) {
        __syncthreads();
        async16(gA + k0,                &As[t * 8]);
        async16(gA + (long)64 * K + k0, &As[2048 + t * 8]);
        async16(gB + k0,                &Bs[t * 8]);
        async16(gB + (long)64 * K + k0, &Bs[2048 + t * 8]);
        __syncthreads();

        bf16x8_t af[4], bf[4];
#pragma unroll
        for (int i = 0; i < 4; i++)
            af[i] = *(const bf16x8_t*)&As[(wm + i * 16 + mn) * 32 + quad * 8];
#pragma unroll
        for (int j = 0; j < 4; j++)
            bf[j] = *(const bf16x8_t*)&Bs[(wn + j * 16 + mn) * 32 + quad * 8];
#pragma unroll
        for (int i = 0; i < 4; i++)
#pragma unroll
            for (int j = 0; j < 4; j++) acc[i][j] = mfma16(af[i], bf[j], acc[i][j]);
    }

    if (OMAP == 0) {
        // fp32 direct stores (dword, 64B segments)
#pragma unroll
        for (int i = 0; i < 4; i++)
#pragma unroll
            for (int j = 0; j < 4; j++)
#pragma unroll
                for (int r = 0; r < 4; r++) {
                    long row = m0 + wm + i * 16 + quad * 4 + r;
                    long col = n0 + wn + j * 16 + mn;
                    C[row * N + col] = (CT)acc[i][j][r];
                }
    } else {
        __syncthreads();   // all waves done reading As/Bs; safe to reuse as staging
        __bf16* stg = (w == 0) ? As : (w == 1) ? Bs : Es[w - 2];
        // LDS element offset with 16B-granule XOR swizzle: (row, col) ->
        //   row*64 + ((col>>3)^(row&7))*8 + (col&7)   -- conflict-free b128 readback
        const bool vpart = (OMAP == 1) && (blockIdx.x >= 8);

        if (OMAP == 2 || !vpart) {
            // stage [sl][d] = acc value (b16 writes)
#pragma unroll
            for (int i = 0; i < 4; i++)
#pragma unroll
                for (int j = 0; j < 4; j++)
#pragma unroll
                    for (int r = 0; r < 4; r++) {
                        int sl = i * 16 + quad * 4 + r;
                        int d  = j * 16 + mn;
                        stg[sl * 64 + (((d >> 3) ^ (sl & 7)) * 8) + (d & 7)] =
                            (__bf16)acc[i][j][r];
                    }
        } else {
            // V-part: stage transposed+permuted [d][p], p=(quad*4+r)*4+i (b64 packs)
            const int b_ = (int)((m0 + wm) >> 12);
#pragma unroll
            for (int r = 0; r < 4; r++) {
                float scl = fmaxf(imp[b_ * 16 + quad * 4 + r], 1e-6f);
#pragma unroll
                for (int j = 0; j < 4; j++) {
                    bf16x4_t pk;
#pragma unroll
                    for (int i = 0; i < 4; i++) pk[i] = (__bf16)(acc[i][j][r] * scl);
                    int d  = j * 16 + mn;
                    int p0 = (quad * 4 + r) * 4;
                    *(bf16x4_t*)&stg[d * 64 + (((p0 >> 3) ^ (d & 7)) * 8) + (p0 & 7)] = pk;
                }
            }
        }

        // readback + coalesced wide stores
        if (OMAP == 2) {
            __bf16* Cg = (__bf16*)C + (m0 + wm) * (long)N + (n0 + wn);
#pragma unroll
            for (int it = 0; it < 8; it++) {
                int rowL = it * 8 + (lane >> 3);
                int cb   = lane & 7;
                bf16x8_t vv = *(const bf16x8_t*)&stg[rowL * 64 + ((cb ^ (rowL & 7)) * 8)];
                *(bf16x8_t*)&Cg[(long)rowL * N + cb * 8] = vv;
            }
        } else {
            const int b_    = (int)((m0 + wm) >> 12);
            const int sbase = (int)((m0 + wm) & 4095);
            __bf16* dst;
            if (!vpart) {
                int h_ = (int)((n0 + wn) >> 6);
                dst = (__bf16*)C + (long)(b_ * 16 + h_) * 262144 + (long)sbase * 64;
            } else {
                int h_ = (int)((n0 + wn) >> 6) - 16;
                dst = V2 + (long)(b_ * 16 + h_) * 262144 + (long)(sbase >> 6) * 4096;
            }
#pragma unroll
            for (int it = 0; it < 8; it++) {
                int rowL = it * 8 + (lane >> 3);
                int cb   = lane & 7;
                bf16x8_t vv = *(const bf16x8_t*)&stg[rowL * 64 + ((cb ^ (rowL & 7)) * 8)];
                *(bf16x8_t*)&dst[rowL * 64 + cb * 8] = vv;
            }
        }
    }
}

// ---------- flash attention: LDS-staged K/V (coalesced async16 + XOR swizzle) ----------
// 1D grid 1024 blocks, XCD-swizzled: gid = (bh&7) | qt<<3 | sp<<7 | (bh>>3)<<8.
__global__ __launch_bounds__(256, 4) void attn_kernel(const __bf16* __restrict__ Qp,
                                                      const __bf16* __restrict__ Kh,
                                                      const __bf16* __restrict__ Vh,
                                                      const float* __restrict__ imp,
                                                      _Float16* __restrict__ Op,
                                                      float* __restrict__ Lp) {
    const int gid = blockIdx.x;
    const int qt  = (gid >> 3) & 15;
    const int sp  = (gid >> 7) & 1;
    const int bh  = ((gid >> 8) << 3) | (gid & 7);
    const int b   = bh >> 4;
    const int h   = bh & 15;
    const int t    = threadIdx.x;
    const int w    = t >> 6;
    const int lane = t & 63;
    const int quad = lane >> 4;
    const int mn   = lane & 15;

    __shared__ __bf16 Ks[64 * 64];
    __shared__ __bf16 Vs[64 * 64];
    __shared__ __bf16 Ps[4][32][72];

    const long qrow0 = (long)b * 2048 + qt * 128 + w * 32;
    const __bf16* Kb = Kh + (long)bh * 262144;
    const __bf16* Vb = Vh + (long)bh * 262144;

    const int r8 = lane >> 3;
    const int cs = (lane & 7) ^ r8;
    const int srcoff0 = (0 * 4 + w) * 512 + r8 * 64 + cs * 8;
    const int srcoff1 = (1 * 4 + w) * 512 + r8 * 64 + cs * 8;
    __bf16* ldsK0 = Ks + (0 * 4 + w) * 512;
    __bf16* ldsK1 = Ks + (1 * 4 + w) * 512;
    __bf16* ldsV0 = Vs + (0 * 4 + w) * 512;
    __bf16* ldsV1 = Vs + (1 * 4 + w) * 512;

    bf16x8_t aq[2][2];
#pragma unroll
    for (int rt = 0; rt < 2; rt++)
#pragma unroll
        for (int x = 0; x < 2; x++)
            aq[rt][x] = *(const bf16x8_t*)&Qp[(qrow0 + rt * 16 + mn) * 1024 + h * 64 + x * 32 + quad * 8];

    const float impc = fmaxf(imp[b * 16 + mn], 1e-6f);

    float lpart[2][4];
    f32x4_t o[2][4];
#pragma unroll
    for (int rt = 0; rt < 2; rt++)
#pragma unroll
        for (int r = 0; r < 4; r++) lpart[rt][r] = 0.f;
#pragma unroll
    for (int rt = 0; rt < 2; rt++)
#pragma unroll
        for (int dt = 0; dt < 4; dt++) o[rt][dt] = (f32x4_t){0.f, 0.f, 0.f, 0.f};

    for (int st = sp * 32; st < sp * 32 + 32; st++) {
        const long kbase = (long)st * 4096;
        __syncthreads();
        async16(Kb + kbase + srcoff0, ldsK0);
        async16(Kb + kbase + srcoff1, ldsK1);
        async16(Vb + kbase + srcoff0, ldsV0);
        async16(Vb + kbase + srcoff1, ldsV1);
        __syncthreads();

        f32x4_t sc[2][4];
        {
            bf16x8_t bk0[4], bk1[4];
#pragma unroll
            for (int ct = 0; ct < 4; ct++) {
                int s  = ct * 16 + mn;
                int c0 = (quad ^ (s & 7)) * 8;
                bk0[ct] = *(const bf16x8_t*)&Ks[s * 64 + c0];
                bk1[ct] = *(const bf16x8_t*)&Ks[s * 64 + (c0 ^ 32)];
            }
#pragma unroll
            for (int rt = 0; rt < 2; rt++) {
#pragma unroll
                for (int ct = 0; ct < 4; ct++) sc[rt][ct] = (f32x4_t){0.f, 0.f, 0.f, 0.f};
#pragma unroll
                for (int ct = 0; ct < 4; ct++) {
                    sc[rt][ct] = mfma16(aq[rt][0], bk0[ct], sc[rt][ct]);
                    sc[rt][ct] = mfma16(aq[rt][1], bk1[ct], sc[rt][ct]);
                }
            }
        }

#pragma unroll
        for (int rt = 0; rt < 2; rt++)
#pragma unroll
            for (int r = 0; r < 4; r++) {
                float p0 = __builtin_amdgcn_exp2f(sc[rt][0][r]);
                float p1 = __builtin_amdgcn_exp2f(sc[rt][1][r]);
                float p2 = __builtin_amdgcn_exp2f(sc[rt][2][r]);
                float p3 = __builtin_amdgcn_exp2f(sc[rt][3][r]);
                lpart[rt][r] += (p0 + p1) + (p2 + p3);
                bf16x4_t pk;
                pk[0] = (__bf16)p0; pk[1] = (__bf16)p1;
                pk[2] = (__bf16)p2; pk[3] = (__bf16)p3;
                *(bf16x4_t*)&Ps[w][rt * 16 + quad * 4 + r][mn * 4] = pk;
            }

        {
            bf16x8_t bv0[4], bv1[4];
#pragma unroll
            for (int dt = 0; dt < 4; dt++) {
                int d  = dt * 16 + mn;
                int c0 = (quad ^ (d & 7)) * 8;
                bv0[dt] = *(const bf16x8_t*)&Vs[d * 64 + c0];
                bv1[dt] = *(const bf16x8_t*)&Vs[d * 64 + (c0 ^ 32)];
            }
#pragma unroll
            for (int rt = 0; rt < 2; rt++) {
                bf16x8_t ap0 = *(const bf16x8_t*)&Ps[w][rt * 16 + mn][quad * 8];
                bf16x8_t ap1 = *(const bf16x8_t*)&Ps[w][rt * 16 + mn][32 + quad * 8];
#pragma unroll
                for (int dt = 0; dt < 4; dt++) {
                    o[rt][dt] = mfma16(ap0, bv0[dt], o[rt][dt]);
                    o[rt][dt] = mfma16(ap1, bv1[dt], o[rt][dt]);
                }
            }
        }
    }

#pragma unroll
    for (int rt = 0; rt < 2; rt++)
#pragma unroll
        for (int r = 0; r < 4; r++) {
            float l = redsum16(lpart[rt][r] * impc);
            long row = qrow0 + rt * 16 + quad * 4 + r;
            if (mn == 0) Lp[((long)sp * 4096 + row) * 16 + h] = l;
#pragma unroll
            for (int dt = 0; dt < 4; dt++)
                Op[((long)sp * 4096 + row) * 1024 + h * 64 + dt * 16 + mn] =
                    (_Float16)o[rt][dt][r];
        }
}

// ---------- combine: Y = (o0+o1)/(l0+l1) ----------
__global__ __launch_bounds__(256) void combine_kernel(const _Float16* __restrict__ Op,
                                                      const float* __restrict__ Lp,
                                                      __bf16* __restrict__ Y) {
    int tid = blockIdx.x * 256 + threadIdx.x;
    int row = tid >> 7;
    int cg  = tid & 127;
    int h   = cg >> 3;
    f16x8_t o0 = *(const f16x8_t*)&Op[(long)row * 1024 + cg * 8];
    f16x8_t o1 = *(const f16x8_t*)&Op[(long)(4096 + row) * 1024 + cg * 8];
    float inv = 1.0f / (Lp[row * 16 + h] + Lp[(4096 + row) * 16 + h]);
    bf16x8_t y;
#pragma unroll
    for (int j = 0; j < 8; j++) y[j] = (__bf16)(((float)o0[j] + (float)o1[j]) * inv);
    *(bf16x8_t*)&Y[(long)row * 1024 + cg * 8] = y;
}

// ---------- launch ----------
extern "C" void kernel_launch(void* const* d_in, const int* in_sizes, int n_in,
                              void* d_out, int out_size, void* d_ws, size_t ws_size,
                              hipStream_t stream) {
    const float* q_f  = (const float*)d_in[0];
    const float* kv_f = (const float*)d_in[1];
    const float* imp  = (const float*)d_in[2];
    const float* wq_f = (const float*)d_in[3];
    const float* wk_f = (const float*)d_in[4];
    const float* wv_f = (const float*)d_in[5];
    const float* wo_f = (const float*)d_in[6];

    char* ws = (char*)d_ws;
    const size_t MB = 1ull << 20;
    __bf16*   qb    = (__bf16*)(ws + 0);            // 8 MB   (stage A)
    __bf16*   kvb   = (__bf16*)(ws + 8 * MB);       // 16 MB  (stage A)
    __bf16*   wqb   = (__bf16*)(ws + 24 * MB);      // 2 MB   (stage A)
    __bf16*   wkvb  = (__bf16*)(ws + 26 * MB);      // 4 MB   (stage A)
    _Float16* Opart = (_Float16*)(ws + 0);          // 16 MB  (stage B)
    float*    Lpart = (float*)(ws + 16 * MB);       // 0.5 MB (stage B)
    __bf16*   Yb    = (__bf16*)(ws + 17 * MB);      // 8 MB   (stage B)
    __bf16*   wob   = (__bf16*)(ws + 30 * MB);      // 2 MB
    __bf16*   Qp    = (__bf16*)(ws + 32 * MB);      // 8 MB
    __bf16*   Khd   = (__bf16*)(ws + 40 * MB);      // 16 MB
    __bf16*   Vhd   = (__bf16*)(ws + 56 * MB);      // 16 MB

    const float QSCALE = 0.125f * 1.4426950408889634f;

    f2b_multi<<<16384, 256, 0, stream>>>(q_f, kv_f, wq_f, wk_f, wv_f, wo_f,
                                         qb, kvb, wqb, wkvb, wob, QSCALE);

    gemm_bt_kernel<2, __bf16><<<dim3(8, 32), 256, 0, stream>>>(qb, wqb, Qp, 4096, 1024, 1024,
                                                               nullptr, nullptr);
    gemm_bt_kernel<1, __bf16><<<dim3(16, 64), 256, 0, stream>>>(kvb, wkvb, Khd, 8192, 2048, 1024,
                                                                Vhd, imp);

    attn_kernel<<<1024, 256, 0, stream>>>(Qp, Khd, Vhd, imp, Opart, Lpart);
    combine_kernel<<<2048, 256, 0, stream>>>(Opart, Lpart, Yb);

    gemm_bt_kernel<0, float><<<dim3(8, 32), 256, 0, stream>>>(Yb, wob, (float*)d_out, 4096, 1024, 1024,
                                                              nullptr, nullptr);
}